// Round 9
// baseline (127.228 us; speedup 1.0000x reference)
//
#include <hip/hip_runtime.h>
#include <hip/hip_bf16.h>

// SignedAttention: B=4,H=8,L=2048,D=64; N_PATCHES=128 (16 ch/patch); keys = patches p+1..p+9.
// Round 9: BARRIER-FREE single-wave blocks. One wave = one (bh,patch); 4096 blocks x 64 thr
// = 16 waves/CU in one round. No shared staging, no cross-wave phase locking: Q/K/V read
// directly from global (fp32), only per-wave LDS is the 5.4 KB A-transform buffer
// (__syncthreads on a 1-wave block is a cheap ordering fence).
// Compute semantics identical to verified R6: value-based masking ONLY (MFMA k-layout is
// unverified; positional masks broke R5), ones-MFMA row sums, E2=rcp(E1), epilogue norm.

#define LSEQ 2048
#define CH   16
#define WIN  9
#define SA   168   // A row pitch (elems); 16*168*2 = 5376 B LDS per block

typedef __attribute__((ext_vector_type(8))) short bf16x8;
typedef __attribute__((ext_vector_type(4))) float f32x4;

union BF8 { bf16x8 v; unsigned int u[4]; };

// bf16 pair pack, round-half-up: low16 = bf16(a), high16 = bf16(b).
__device__ __forceinline__ unsigned int bfpack(float a, float b) {
  unsigned int ua = (__float_as_uint(a) + 0x8000u) >> 16;
  unsigned int ub = (__float_as_uint(b) + 0x8000u) & 0xFFFF0000u;
  return ua | ub;
}

__device__ __forceinline__ bf16x8 pack8(float4 a, float4 b) {
  BF8 r;
  r.u[0] = bfpack(a.x, a.y);
  r.u[1] = bfpack(a.z, a.w);
  r.u[2] = bfpack(b.x, b.y);
  r.u[3] = bfpack(b.z, b.w);
  return r.v;
}

__global__ __launch_bounds__(64, 4)
void signed_attn_kernel(const float* __restrict__ Q,
                        const float* __restrict__ K,
                        const float* __restrict__ V,
                        const float* __restrict__ LS,
                        float* __restrict__ O) {
  __shared__ __align__(16) unsigned short As[16 * SA];   // per-wave A (C->A layout bounce)

  const int p  = blockIdx.x & 127;
  const int bh = blockIdx.x >> 7;
  const int l  = threadIdx.x;        // 0..63
  const int lr = l & 15;
  const int q4 = l >> 4;

  float* Og = O + ((size_t)bh * LSEQ + (size_t)p * CH) * 64;
  const int npk = (127 - p) < WIN ? (127 - p) : WIN;

  if (npk == 0) {   // p = 127: fully masked -> softmaxes cancel -> exact 0
#pragma unroll
    for (int n = 0; n < 4; n++)
#pragma unroll
      for (int r = 0; r < 4; r++)
        Og[(q4 * 4 + r) * 64 + n * 16 + lr] = 0.f;
    return;
  }

  const int c0     = (p + 1) * CH;    // key-window start row
  const int maxoff = 2047 - c0;       // >= 15 for p <= 126; clamped rows are value-masked
  const float scale = fminf(30.f, fmaxf(1.f, __expf(LS[0]))) * 0.125f;

  // ---- Q fragments (A operand): lane (m=lr, kgrp=q4), 8 contiguous dims ----
  const float* Qg = Q + ((size_t)bh * LSEQ + (size_t)p * CH) * 64;
  bf16x8 qa[2];
#pragma unroll
  for (int s = 0; s < 2; s++) {
    const float* qp = Qg + lr * 64 + q4 * 8 + 32 * s;
    qa[s] = pack8(*(const float4*)qp, *(const float4*)(qp + 4));
  }

  // ---- QK^T per tile -> e1 -> A LDS immediately (no sacc array: 9 independent tiles) ----
  const float* Kb = K + ((size_t)bh * LSEQ + c0) * 64;
#pragma unroll
  for (int tl = 0; tl < WIN; tl++) {
    int ro = tl * 16 + lr;
    ro = ro < maxoff ? ro : maxoff;                 // in-bounds; clamped rows masked below
    const float* kp = Kb + (size_t)ro * 64 + q4 * 8;
    f32x4 acc = {0.f, 0.f, 0.f, 0.f};
#pragma unroll
    for (int s = 0; s < 2; s++) {
      bf16x8 b = pack8(*(const float4*)(kp + 32 * s), *(const float4*)(kp + 32 * s + 4));
      acc = __builtin_amdgcn_mfma_f32_16x16x32_bf16(qa[s], b, acc, 0, 0, 0);
    }
    const bool val = tl < npk;
#pragma unroll
    for (int r = 0; r < 4; r++) {                   // C layout: row=q4*4+r, col=tl*16+lr
      float e1 = __expf(scale * acc[r]);            // scale*s in +-~11: fp32-safe (R4+)
      unsigned int u = (__float_as_uint(e1) + 0x8000u) >> 16;
      As[(q4 * 4 + r) * SA + tl * 16 + lr] = (unsigned short)(val ? u : 0u);
    }
  }
#pragma unroll
  for (int r = 0; r < 4; r++)                       // zero-pad cols 144..159 (k-step 4)
    As[(q4 * 4 + r) * SA + 144 + lr] = 0;

  __syncthreads();   // single-wave block: cheap fence ordering ds_write -> ds_read

  // ---- PV + row sums by MFMA: O1=E1*V, O2=E2*V, S1=E1*1, S2=E2*1 (all-ones B) ----
  BF8 bones;
#pragma unroll
  for (int j = 0; j < 4; j++) bones.u[j] = 0x3F803F80u;

  f32x4 o1[4] = {{0,0,0,0},{0,0,0,0},{0,0,0,0},{0,0,0,0}};
  f32x4 o2[4] = {{0,0,0,0},{0,0,0,0},{0,0,0,0},{0,0,0,0}};
  f32x4 s1 = {0,0,0,0}, s2 = {0,0,0,0};

  const float* Vb = V + ((size_t)bh * LSEQ + c0) * 64;
#pragma unroll
  for (int s = 0; s < 5; s++) {
    BF8 a1, a2;
    a1.v = *(const bf16x8*)&As[lr * SA + s * 32 + q4 * 8];
    // a2 = elementwise 1/a1 (e2 = exp(-x) = rcp(e1)); bits==0 (masked) -> 0, not inf.
#pragma unroll
    for (int j = 0; j < 4; j++) {
      unsigned int d    = a1.u[j];
      unsigned int lo16 = d << 16;
      unsigned int hi16 = d & 0xFFFF0000u;
      float lo = __uint_as_float(lo16);
      float hi = __uint_as_float(hi16);
      float rl = (lo16 == 0u) ? 0.f : __builtin_amdgcn_rcpf(lo);
      float rh = (hi16 == 0u) ? 0.f : __builtin_amdgcn_rcpf(hi);
      a2.u[j] = bfpack(rl, rh);
    }
    s1 = __builtin_amdgcn_mfma_f32_16x16x32_bf16(a1.v, bones.v, s1, 0, 0, 0);
    s2 = __builtin_amdgcn_mfma_f32_16x16x32_bf16(a2.v, bones.v, s2, 0, 0, 0);

    // V B-fragments from global: lane (n-col = lr, kgrp = q4) needs rows rb..rb+7 in the
    // SAME j-order as the A b128 memory order -> k-permutation cancels (f-independent).
    int rof[8];
#pragma unroll
    for (int j = 0; j < 8; j++) {
      int ro = s * 32 + q4 * 8 + j;
      rof[j] = ro < maxoff ? ro : maxoff;           // clamped rows have A=0
    }
#pragma unroll
    for (int n = 0; n < 4; n++) {
      float v[8];
#pragma unroll
      for (int j = 0; j < 8; j++) v[j] = Vb[(size_t)rof[j] * 64 + n * 16 + lr];
      BF8 b;
      b.u[0] = bfpack(v[0], v[1]);
      b.u[1] = bfpack(v[2], v[3]);
      b.u[2] = bfpack(v[4], v[5]);
      b.u[3] = bfpack(v[6], v[7]);
      o1[n] = __builtin_amdgcn_mfma_f32_16x16x32_bf16(a1.v, b.v, o1[n], 0, 0, 0);
      o2[n] = __builtin_amdgcn_mfma_f32_16x16x32_bf16(a2.v, b.v, o2[n], 0, 0, 0);
    }
  }

  // ---- epilogue: O = O1*rcp(S1) - O2*rcp(S2); row sums lane-aligned with O ----
#pragma unroll
  for (int r = 0; r < 4; r++) {
    float rp = __builtin_amdgcn_rcpf(s1[r]);
    float rn = __builtin_amdgcn_rcpf(s2[r]);
#pragma unroll
    for (int n = 0; n < 4; n++)
      Og[(q4 * 4 + r) * 64 + n * 16 + lr] = o1[n][r] * rp - o2[n][r] * rn;
  }
}

extern "C" void kernel_launch(void* const* d_in, const int* in_sizes, int n_in,
                              void* d_out, int out_size, void* d_ws, size_t ws_size,
                              hipStream_t stream) {
  const float* Q  = (const float*)d_in[0];
  const float* K  = (const float*)d_in[1];
  const float* V  = (const float*)d_in[2];
  const float* LS = (const float*)d_in[3];
  float* O = (float*)d_out;
  // 32 bh * 128 patches = 4096 single-wave blocks = 16 waves/CU, one resident round
  signed_attn_kernel<<<dim3(4096), dim3(64), 0, stream>>>(Q, K, V, LS, O);
}